// Round 1
// baseline (1116.453 us; speedup 1.0000x reference)
//
#include <hip/hip_runtime.h>
#include <hip/hip_bf16.h>

#define NTOK  49
#define NPAD  64
#define CDIM  256
#define NHEAD 8
#define HDIM  32
#define SCALE 0.17677669529663687f   // 1/sqrt(32)
#define L2E   1.4426950408889634f

typedef __attribute__((ext_vector_type(8))) short bf16x8;
typedef __attribute__((ext_vector_type(4))) short bf16x4;
typedef __attribute__((ext_vector_type(4))) float f32x4;

// fp32 -> bf16 round-to-nearest-even (no NaNs in this workload)
__device__ __forceinline__ unsigned short f2b(float f) {
  unsigned int u = __float_as_uint(f);
  u = (u + 0x7fffu + ((u >> 16) & 1u)) >> 16;
  return (unsigned short)u;
}

// ---------------- K0: prep (bias gather+pad, mask pad, weight bf16 convert) ---
__global__ void swin_prep(const float* __restrict__ mask,
                          const float* __restrict__ qkv_w,
                          const float* __restrict__ rpe,
                          const float* __restrict__ out_w,
                          const int* __restrict__ rel_index,
                          float* __restrict__ bias_pad,        // [8][64][64]
                          float* __restrict__ mask_pad,        // [64][64][64]
                          unsigned short* __restrict__ qkv_wb, // [768][256] bf16
                          unsigned short* __restrict__ out_wb) // [256][256] bf16
{
  int i = blockIdx.x * 256 + threadIdx.x;   // grid = 1024 blocks -> i < 262144
  {
    int w = i >> 12, n = (i >> 6) & 63, m = i & 63;
    float v = 0.f;
    if (n < NTOK && m < NTOK) v = mask[w * (NTOK * NTOK) + n * NTOK + m];
    mask_pad[i] = v;
  }
  if (i < NHEAD * 64 * 64) {
    int h = i >> 12, n = (i >> 6) & 63, m = i & 63;
    float v = -1e30f;  // padded keys get -inf-ish logits -> exp = 0
    if (n < NTOK && m < NTOK) v = rpe[rel_index[n * NTOK + m] * NHEAD + h];
    bias_pad[i] = v;
  }
  if (i < 768 * CDIM) qkv_wb[i] = f2b(qkv_w[i]);
  if (i < CDIM * CDIM) out_wb[i] = f2b(out_w[i]);
}

// ---------------- K1: fused QKV projection + windowed attention ---------------
// One workgroup (4 waves) per window. ctx (bf16) is packed into the second half
// of each 1KB output row of d_out; K2 consumes and overwrites it.
__global__ __launch_bounds__(256, 2)
void swin_qkv_attn(const float* __restrict__ x,
                   const float* __restrict__ qkv_b,
                   const unsigned short* __restrict__ qkv_wb,
                   const float* __restrict__ bias_pad,
                   const float* __restrict__ mask_pad,
                   unsigned short* outus)
{
  __shared__ __align__(16) unsigned short xb[NPAD][CDIM + 8];  // 33792 B x bf16
  __shared__ __align__(16) unsigned short wp[96][72];          // 13824 B weight K-chunk
  __shared__ __align__(16) unsigned short qh[NPAD][40];        //  5120 B q (scaled)
  __shared__ __align__(16) unsigned short kh[NPAD][40];        //  5120 B k
  __shared__ __align__(16) unsigned short vT[HDIM][72];        //  4608 B v transposed
  __shared__ __align__(16) unsigned short pl[NPAD][72];        //  9216 B probs
  __shared__ __align__(16) unsigned short cs[NPAD][40];        //  5120 B ctx stage
  // total 76800 B -> 2 WG/CU

  const int b    = blockIdx.x;
  const int tid  = threadIdx.x;
  const int lane = tid & 63;
  const int wv   = tid >> 6;    // wave id 0..3 = M-tile = query n-tile
  const int l16  = lane & 15;
  const int g4   = lane >> 4;

  const float* xw = x + (size_t)b * (NTOK * CDIM);

  // stage x -> bf16 LDS, zero the 15 pad rows
  for (int i = tid; i < NTOK * CDIM / 4; i += 256) {
    int row = i >> 6, c4 = i & 63;
    float4 v = *reinterpret_cast<const float4*>(xw + row * CDIM + c4 * 4);
    bf16x4 o = { (short)f2b(v.x), (short)f2b(v.y), (short)f2b(v.z), (short)f2b(v.w) };
    *reinterpret_cast<bf16x4*>(&xb[row][c4 * 4]) = o;
  }
  for (int i = tid; i < (NPAD - NTOK) * CDIM / 4; i += 256) {
    int row = NTOK + (i >> 6), c4 = i & 63;
    bf16x4 z = {0, 0, 0, 0};
    *reinterpret_cast<bf16x4*>(&xb[row][c4 * 4]) = z;
  }

  const float* maskw = mask_pad + (size_t)(b & 63) * 4096;

  for (int h = 0; h < NHEAD; ++h) {
    // ---- per-head QKV GEMM: [64 tok] x [256 K] -> [96 cols: q|k|v of head h]
    f32x4 acc[6];
#pragma unroll
    for (int t = 0; t < 6; ++t) acc[t] = (f32x4){0.f, 0.f, 0.f, 0.f};

    for (int ck = 0; ck < 4; ++ck) {          // K chunks of 64
      __syncthreads();                         // protect wp / cs / qh-kh-vT reuse
      for (int i = tid; i < 96 * 16; i += 256) {
        int rr = i >> 4, c4 = i & 15;
        int grow = ((rr >> 5) << 8) + h * HDIM + (rr & 31);  // q/k/v row gather
        bf16x4 v = *reinterpret_cast<const bf16x4*>(
            qkv_wb + (size_t)grow * CDIM + ck * 64 + c4 * 4);
        *reinterpret_cast<bf16x4*>(&wp[rr][c4 * 4]) = v;
      }
      __syncthreads();
#pragma unroll
      for (int ks = 0; ks < 2; ++ks) {
        bf16x8 a = *reinterpret_cast<const bf16x8*>(
            &xb[wv * 16 + l16][ck * 64 + ks * 32 + g4 * 8]);
#pragma unroll
        for (int nt = 0; nt < 6; ++nt) {
          bf16x8 bb = *reinterpret_cast<const bf16x8*>(&wp[nt * 16 + l16][ks * 32 + g4 * 8]);
          acc[nt] = __builtin_amdgcn_mfma_f32_16x16x32_bf16(a, bb, acc[nt], 0, 0, 0);
        }
      }
    }

    // epilogue: +bias, scale q, scatter to qh / kh / vT (v transposed)
#pragma unroll
    for (int nt = 0; nt < 6; ++nt) {
      int sec = nt >> 1;                       // 0=q 1=k 2=v
      int d = (nt * 16 + l16) & 31;
      float bias = qkv_b[sec * CDIM + h * HDIM + d];
#pragma unroll
      for (int r = 0; r < 4; ++r) {
        int row = wv * 16 + g4 * 4 + r;
        float val = acc[nt][r] + bias;
        if (sec == 0)      qh[row][d] = f2b(val * SCALE);
        else if (sec == 1) kh[row][d] = f2b(val);
        else               vT[d][row] = f2b(val);
      }
    }
    __syncthreads();

    // ---- S^T = K·Q^T  (D[row=m][col=n]); wave wv owns query rows wv*16..+15
    f32x4 s[4];
    {
      bf16x8 qf = *reinterpret_cast<const bf16x8*>(&qh[wv * 16 + l16][g4 * 8]);
#pragma unroll
      for (int mt = 0; mt < 4; ++mt) {
        bf16x8 kf = *reinterpret_cast<const bf16x8*>(&kh[mt * 16 + l16][g4 * 8]);
        s[mt] = __builtin_amdgcn_mfma_f32_16x16x32_bf16(kf, qf, (f32x4){0.f,0.f,0.f,0.f}, 0, 0, 0);
      }
    }
    const int n = wv * 16 + l16;               // query index (col of D)
    const float* bh = bias_pad + h * 4096;
    float p[4][4];
    float mx = -3e38f;
#pragma unroll
    for (int mt = 0; mt < 4; ++mt)
#pragma unroll
      for (int r = 0; r < 4; ++r) {
        int m = mt * 16 + g4 * 4 + r;          // key index (row of D)
        float v = s[mt][r] + bh[n * 64 + m] + maskw[n * 64 + m];
        p[mt][r] = v;
        mx = fmaxf(mx, v);
      }
    // softmax over m: 16 lane-local values + 4 lane-groups via shfl_xor(16,32)
    mx = fmaxf(mx, __shfl_xor(mx, 16));
    mx = fmaxf(mx, __shfl_xor(mx, 32));
    float sum = 0.f;
#pragma unroll
    for (int mt = 0; mt < 4; ++mt)
#pragma unroll
      for (int r = 0; r < 4; ++r) {
        float e = exp2f((p[mt][r] - mx) * L2E);
        p[mt][r] = e;
        sum += e;
      }
    sum += __shfl_xor(sum, 16);
    sum += __shfl_xor(sum, 32);
    float inv = 1.f / sum;
#pragma unroll
    for (int mt = 0; mt < 4; ++mt) {
      bf16x4 pv = { (short)f2b(p[mt][0] * inv), (short)f2b(p[mt][1] * inv),
                    (short)f2b(p[mt][2] * inv), (short)f2b(p[mt][3] * inv) };
      *reinterpret_cast<bf16x4*>(&pl[n][mt * 16 + g4 * 4]) = pv;  // pl[n][m]
    }

    // ---- PV: ctx[n][d] = sum_m P[n][m] V[m][d]
#pragma unroll
    for (int dt = 0; dt < 2; ++dt) {
      f32x4 c = {0.f, 0.f, 0.f, 0.f};
#pragma unroll
      for (int ks = 0; ks < 2; ++ks) {
        bf16x8 pa = *reinterpret_cast<const bf16x8*>(&pl[wv * 16 + l16][ks * 32 + g4 * 8]);
        bf16x8 vb = *reinterpret_cast<const bf16x8*>(&vT[dt * 16 + l16][ks * 32 + g4 * 8]);
        c = __builtin_amdgcn_mfma_f32_16x16x32_bf16(pa, vb, c, 0, 0, 0);
      }
#pragma unroll
      for (int r = 0; r < 4; ++r)
        cs[wv * 16 + g4 * 4 + r][dt * 16 + l16] = f2b(c[r]);
    }
    __syncthreads();

    // coalesced ctx store: bf16 packed into second half of each d_out row
    for (int i = tid; i < NTOK * 8; i += 256) {
      int nn = i >> 3, c4 = i & 7;
      bf16x4 v = *reinterpret_cast<const bf16x4*>(&cs[nn][c4 * 4]);
      *reinterpret_cast<bf16x4*>(
          outus + (size_t)(b * NTOK + nn) * 512 + 256 + h * HDIM + c4 * 4) = v;
    }
  }
}

// ---------------- K2: output projection (full-N 128-row tiles) ----------------
// Stages its own ctx rows into LDS, then overwrites the same rows with fp32 out.
__global__ __launch_bounds__(256, 2)
void swin_proj(const unsigned short* __restrict__ out_wb,
               const float* __restrict__ out_b,
               float* out, const unsigned short* outus)
{
  __shared__ __align__(16) unsigned short actx[128][72];  // 18432 B
  __shared__ __align__(16) unsigned short wb[256][72];    // 36864 B

  const int tid  = threadIdx.x;
  const int lane = tid & 63;
  const int wv   = tid >> 6;
  const int l16  = lane & 15;
  const int g4   = lane >> 4;
  const size_t g0 = (size_t)blockIdx.x * 128;

  f32x4 acc[2][16];
#pragma unroll
  for (int a = 0; a < 2; ++a)
#pragma unroll
    for (int nt = 0; nt < 16; ++nt) acc[a][nt] = (f32x4){0.f, 0.f, 0.f, 0.f};

  for (int ck = 0; ck < 4; ++ck) {            // K chunks of 64
    __syncthreads();
    for (int i = tid; i < 128 * 16; i += 256) {
      int row = i >> 4, c4 = i & 15;
      bf16x4 v = *reinterpret_cast<const bf16x4*>(
          outus + (g0 + row) * 512 + 256 + ck * 64 + c4 * 4);
      *reinterpret_cast<bf16x4*>(&actx[row][c4 * 4]) = v;
    }
    for (int i = tid; i < 256 * 16; i += 256) {
      int e = i >> 4, c4 = i & 15;
      bf16x4 v = *reinterpret_cast<const bf16x4*>(
          out_wb + (size_t)e * CDIM + ck * 64 + c4 * 4);
      *reinterpret_cast<bf16x4*>(&wb[e][c4 * 4]) = v;
    }
    __syncthreads();
#pragma unroll
    for (int ks = 0; ks < 2; ++ks) {
      bf16x8 a0 = *reinterpret_cast<const bf16x8*>(&actx[(wv * 2 + 0) * 16 + l16][ks * 32 + g4 * 8]);
      bf16x8 a1 = *reinterpret_cast<const bf16x8*>(&actx[(wv * 2 + 1) * 16 + l16][ks * 32 + g4 * 8]);
#pragma unroll
      for (int nt = 0; nt < 16; ++nt) {
        bf16x8 bb = *reinterpret_cast<const bf16x8*>(&wb[nt * 16 + l16][ks * 32 + g4 * 8]);
        acc[0][nt] = __builtin_amdgcn_mfma_f32_16x16x32_bf16(a0, bb, acc[0][nt], 0, 0, 0);
        acc[1][nt] = __builtin_amdgcn_mfma_f32_16x16x32_bf16(a1, bb, acc[1][nt], 0, 0, 0);
      }
    }
  }

#pragma unroll
  for (int a = 0; a < 2; ++a)
#pragma unroll
    for (int nt = 0; nt < 16; ++nt) {
      int e = nt * 16 + l16;
      float ob = out_b[e];
#pragma unroll
      for (int r = 0; r < 4; ++r) {
        size_t gg = g0 + (size_t)(wv * 2 + a) * 16 + g4 * 4 + r;
        out[gg * CDIM + e] = acc[a][nt][r] + ob;
      }
    }
}

extern "C" void kernel_launch(void* const* d_in, const int* in_sizes, int n_in,
                              void* d_out, int out_size, void* d_ws, size_t ws_size,
                              hipStream_t stream) {
  (void)in_sizes; (void)n_in; (void)out_size; (void)ws_size;
  const float* x        = (const float*)d_in[0];
  const float* mask     = (const float*)d_in[1];
  const float* qkv_w    = (const float*)d_in[2];
  const float* qkv_b    = (const float*)d_in[3];
  const float* rpe      = (const float*)d_in[4];
  const float* out_w    = (const float*)d_in[5];
  const float* out_b    = (const float*)d_in[6];
  const int*   rel_idx  = (const int*)d_in[7];
  float* out = (float*)d_out;

  char* ws = (char*)d_ws;
  float* bias_pad         = (float*)(ws);                       // 131072 B
  float* mask_pad         = (float*)(ws + 131072);              // 1048576 B
  unsigned short* qkv_wb  = (unsigned short*)(ws + 1179648);    // 393216 B
  unsigned short* out_wb  = (unsigned short*)(ws + 1572864);    // 131072 B
  // total ws use: 1703936 B

  hipLaunchKernelGGL(swin_prep, dim3(1024), dim3(256), 0, stream,
                     mask, qkv_w, rpe, out_w, rel_idx,
                     bias_pad, mask_pad, qkv_wb, out_wb);
  hipLaunchKernelGGL(swin_qkv_attn, dim3(4096), dim3(256), 0, stream,
                     x, qkv_b, qkv_wb, bias_pad, mask_pad, (unsigned short*)d_out);
  hipLaunchKernelGGL(swin_proj, dim3(1568), dim3(256), 0, stream,
                     out_wb, out_b, out, (unsigned short*)d_out);
}